// Round 1
// 62.626 us; speedup vs baseline: 1.0027x; 1.0027x over previous
//
#include <hip/hip_runtime.h>
#include <cmath>

#define IH 128
#define IW 128
#define NL 256          // strokes per batch image
#define NB 4            // batch
#define NS (NB * NL)    // 1024 strokes total
#define BSZ 512         // brush resolution

// Bilinear tap exactly like reference: load clipped, zero if out of range.
__device__ __forceinline__ float bil_tap(const float* __restrict__ br, int ix, int iy) {
    int cx = min(max(ix, 0), BSZ - 1);
    int cy = min(max(iy, 0), BSZ - 1);
    float v = br[cy * BSZ + cx];
    bool ok = ((unsigned)ix < (unsigned)BSZ) && ((unsigned)iy < (unsigned)BSZ);
    return ok ? v : 0.0f;
}

// ------- fused single kernel: warp prep in LDS + 8 px/wave render ----------
// Phase 0: thread t computes the warp matrix of stroke (b, t) straight into
//          LDS (identical rounding sequence to the old prep_strokes, DP
//          sincos -> correctly-rounded f32, so outputs are bit-identical).
// Phase 1: unchanged coverage scan (see round 6/7 proofs from prior session):
//   rint(xq) in [0,512)  <=>  gx in [-1, 1)   (monotone fl-chain)
//   AND over 3x3 erosion taps == 4 range checks on separable min/max
//   inactive border taps (erosion pad) duplicate the center via xse/yse subst.
__global__ __launch_bounds__(256) void render_strokes(
    const float* __restrict__ brushes,  // (2,1,512,512)
    const float* __restrict__ params,   // (4,256,8)
    float* __restrict__ out)            // (4,3,128,128)
{
    __shared__ float sp[6 * NL];        // [k][stroke], k=0..5

    const int t  = threadIdx.x;
    const int b  = blockIdx.x >> 9;     // 512 blocks per batch (32 px/block)
    const int sb = b * NL;

    // ---- fused warp prep: stroke sb+t -> sp[k][t] (exact ref ordering) ----
    {
        const float* __restrict__ p = params + (size_t)(sb + t) * 8;
        float x0 = p[0], y0 = p[1], w = p[2], h = p[3], th = p[4];
        float ang = __fmul_rn(3.14159265358979323846f, th);
        double ds, dc;
        sincos((double)ang, &ds, &dc);  // correctly-rounded f32 after cast
        float sin_t = (float)ds;
        float cos_t = (float)dc;
        float a_x = __fsub_rn(1.0f, __fmul_rn(2.0f, x0));
        float a_y = __fsub_rn(1.0f, __fmul_rn(2.0f, y0));
        // H==W==128 -> the H/W aspect factors are exactly 1.0
        sp[0 * NL + t] = __fdiv_rn(cos_t, w);
        sp[1 * NL + t] = __fdiv_rn(sin_t, w);
        sp[2 * NL + t] = __fadd_rn(__fdiv_rn(__fmul_rn(a_x, cos_t), w),
                                   __fdiv_rn(__fmul_rn(a_y, sin_t), w));
        sp[3 * NL + t] = __fdiv_rn(-sin_t, h);
        sp[4 * NL + t] = __fdiv_rn(cos_t, h);
        sp[5 * NL + t] = __fsub_rn(__fdiv_rn(__fmul_rn(a_y, cos_t), h),
                                   __fdiv_rn(__fmul_rn(a_x, sin_t), h));
    }
    __syncthreads();

    const int lane = t & 63;
    const int wid  = t >> 6;
    const int wave = blockIdx.x * 4 + wid;      // 0..8191
    const int g    = lane >> 3;                 // pixel group 0..7
    const int j    = lane & 7;                  // stroke sub-index 0..7
    const int P    = wave * 8 + g;              // global pixel id 0..65535
    const int pix  = P & 16383;
    const int py   = pix >> 7;
    const int px   = pix & 127;

    // per-pixel constants (uniform within each 8-lane group)
    float xs1, ys1, xse[3], yse[3];
    {
        float xs[3], ys[3];
#pragma unroll
        for (int d = 0; d < 3; ++d) {
            int qx = px + d - 1, qy = py + d - 1;
            xs[d] = (2.0f * (float)qx + 1.0f) / 128.0f - 1.0f;   // exact in f32
            ys[d] = (2.0f * (float)qy + 1.0f) / 128.0f - 1.0f;
        }
        xs1 = xs[1]; ys1 = ys[1];
        // inactive erosion taps duplicate the (always-active) center coord
#pragma unroll
        for (int d = 0; d < 3; ++d) {
            int qx = px + d - 1, qy = py + d - 1;
            xse[d] = ((qx >= 0) && (qx < IW)) ? xs[d] : xs1;
            yse[d] = ((qy >= 0) && (qy < IH)) ? ys[d] : ys1;
        }
    }

    const size_t pixo = (size_t)py * IW + px;
    const size_t img  = (size_t)b * 3 * IH * IW;
    bool gfound = false;

    for (int c = 0; c < 32; ++c) {
        bool cov = false;
        int ls = 0;

        if (!gfound) {
            ls = (NL - 8 - 8 * c) + j;          // local stroke id, chunk from top
            const float w00 = sp[0 * NL + ls];
            const float w01 = sp[1 * NL + ls];
            const float w02 = sp[2 * NL + ls];
            const float w10 = sp[3 * NL + ls];
            const float w11 = sp[4 * NL + ls];
            const float w12 = sp[5 * NL + ls];

            float ax0 = __fmul_rn(xse[0], w00), ax1 = __fmul_rn(xse[1], w00), ax2 = __fmul_rn(xse[2], w00);
            float by0 = __fmul_rn(yse[0], w01), by1 = __fmul_rn(yse[1], w01), by2 = __fmul_rn(yse[2], w01);
            float cx0 = __fmul_rn(xse[0], w10), cx1 = __fmul_rn(xse[1], w10), cx2 = __fmul_rn(xse[2], w10);
            float dy0 = __fmul_rn(yse[0], w11), dy1 = __fmul_rn(yse[1], w11), dy2 = __fmul_rn(yse[2], w11);

            float axm = fminf(fminf(ax0, ax1), ax2), axM = fmaxf(fmaxf(ax0, ax1), ax2);
            float bym = fminf(fminf(by0, by1), by2), byM = fmaxf(fmaxf(by0, by1), by2);
            float cxm = fminf(fminf(cx0, cx1), cx2), cxM = fmaxf(fmaxf(cx0, cx1), cx2);
            float dym = fminf(fminf(dy0, dy1), dy2), dyM = fmaxf(fmaxf(dy0, dy1), dy2);

            float gxmin = __fadd_rn(__fadd_rn(axm, bym), w02);
            float gxmax = __fadd_rn(__fadd_rn(axM, byM), w02);
            float gymin = __fadd_rn(__fadd_rn(cxm, dym), w12);
            float gymax = __fadd_rn(__fadd_rn(cxM, dyM), w12);

            cov = (gxmin >= -1.0f) && (gxmax < 1.0f) &&
                  (gymin >= -1.0f) && (gymax < 1.0f);
        }

        const unsigned long long m = __ballot(cov);
        const unsigned mg = (unsigned)(m >> (g * 8)) & 0xFFu;

        if (!gfound && mg != 0u) {
            const int jw = 31 - __clz(mg);      // highest covering stroke in chunk
            if (j == jw) {
                // winner: fetch brush pick + colors from params directly
                const float* __restrict__ p = params + ((size_t)(sb + ls)) * 8;
                const float* __restrict__ br =
                    brushes + ((p[3] > p[2]) ? 0 : BSZ * BSZ);  // idx=where(h>w,0,1)
                const float w00 = sp[0 * NL + ls];
                const float w01 = sp[1 * NL + ls];
                const float w02 = sp[2 * NL + ls];
                const float w10 = sp[3 * NL + ls];
                const float w11 = sp[4 * NL + ls];
                const float w12 = sp[5 * NL + ls];
                float gx = __fadd_rn(__fadd_rn(__fmul_rn(xs1, w00), __fmul_rn(ys1, w01)), w02);
                float gy = __fadd_rn(__fadd_rn(__fmul_rn(xs1, w10), __fmul_rn(ys1, w11)), w12);
                float xq = __fmul_rn(__fsub_rn(__fmul_rn(__fadd_rn(gx, 1.0f), 512.0f), 1.0f), 0.5f);
                float yq = __fmul_rn(__fsub_rn(__fmul_rn(__fadd_rn(gy, 1.0f), 512.0f), 1.0f), 0.5f);
                float xf = floorf(xq), yf = floorf(yq);
                int   x0i = (int)xf, y0i = (int)yf;
                float wx1 = __fsub_rn(xq, xf), wy1 = __fsub_rn(yq, yf);
                float wx0 = __fsub_rn(1.0f, wx1), wy0 = __fsub_rn(1.0f, wy1);
                float v00 = bil_tap(br, x0i,     y0i);
                float v10 = bil_tap(br, x0i + 1, y0i);
                float v01 = bil_tap(br, x0i,     y0i + 1);
                float v11 = bil_tap(br, x0i + 1, y0i + 1);
                float sv = __fadd_rn(__fadd_rn(__fadd_rn(
                               __fmul_rn(v00, __fmul_rn(wx0, wy0)),
                               __fmul_rn(v10, __fmul_rn(wx1, wy0))),
                               __fmul_rn(v01, __fmul_rn(wx0, wy1))),
                               __fmul_rn(v11, __fmul_rn(wx1, wy1)));
                out[img + 0 * (IH * IW) + pixo] = __fmul_rn(sv, p[5]);
                out[img + 1 * (IH * IW) + pixo] = __fmul_rn(sv, p[6]);
                out[img + 2 * (IH * IW) + pixo] = __fmul_rn(sv, p[7]);
            }
            gfound = true;
        }

        if (__ballot(!gfound) == 0ull) break;
    }

    if (!gfound && j == 0) {
        out[img + 0 * (IH * IW) + pixo] = 0.0f;
        out[img + 1 * (IH * IW) + pixo] = 0.0f;
        out[img + 2 * (IH * IW) + pixo] = 0.0f;
    }
}

extern "C" void kernel_launch(void* const* d_in, const int* in_sizes, int n_in,
                              void* d_out, int out_size, void* d_ws, size_t ws_size,
                              hipStream_t stream) {
    const float* params  = (const float*)d_in[0];   // (4,256,8) f32
    const float* brushes = (const float*)d_in[1];   // (2,1,512,512) f32
    float* out = (float*)d_out;                     // (4,3,128,128) f32
    (void)d_ws; (void)ws_size;                      // workspace no longer used

    // 65536 pixels / (8 pixels per wave * 4 waves per block) = 2048 blocks
    render_strokes<<<2048, 256, 0, stream>>>(brushes, params, out);
}

// Round 2
// 62.238 us; speedup vs baseline: 1.0090x; 1.0062x over previous
//
#include <hip/hip_runtime.h>
#include <cmath>

#define IH 128
#define IW 128
#define NL 256          // strokes per batch image
#define NB 4            // batch
#define NS (NB * NL)    // 1024 strokes total
#define BSZ 512         // brush resolution

// Bilinear tap exactly like reference: load clipped, zero if out of range.
__device__ __forceinline__ float bil_tap(const float* __restrict__ br, int ix, int iy) {
    int cx = min(max(ix, 0), BSZ - 1);
    int cy = min(max(iy, 0), BSZ - 1);
    float v = br[cy * BSZ + cx];
    bool ok = ((unsigned)ix < (unsigned)BSZ) && ((unsigned)iy < (unsigned)BSZ);
    return ok ? v : 0.0f;
}

// ------- fused single kernel: warp prep in LDS + 8 px/wave render ----------
// Phase 0: thread t computes the warp matrix of stroke (b, t) straight into
//          LDS (DP sincos -> correctly-rounded f32, bit-identical to ref
//          rounding sequence), plus colors and brush-pick offset so the
//          winner path never re-touches params in global memory.
// Phase 1: coverage scan (proofs from prior session):
//   rint(xq) in [0,512)  <=>  gx in [-1, 1)   (monotone fl-chain)
//   AND over 3x3 erosion taps == 4 range checks on separable min/max
//   inactive border taps (erosion pad) duplicate the center via xse/yse subst.
//   xse/yse are monotone (xse[0]<=xse[1]<=xse[2]), so the min/max tap of
//   xse[d]*w is an endpoint selected by sign(w) — bit-equal to the 3-tap
//   min/max since __fmul_rn by a constant is monotone; +-0 sign differences
//   cannot flip the [-1,1) range tests.
// Phase 2 (NEW): epilogue deferred out of the loop. The scan only records
//   the winning stroke; afterwards all <=8 winner lanes of the wave issue
//   their brush taps CONCURRENTLY — one cold-HBM latency exposure per wave
//   instead of up to 8 serialized ones (the 268MB workspace re-poison
//   evicts L2+L3, so brush taps are ~900cy HBM misses).
__global__ __launch_bounds__(256) void render_strokes(
    const float* __restrict__ brushes,  // (2,1,512,512)
    const float* __restrict__ params,   // (4,256,8)
    float* __restrict__ out)            // (4,3,128,128)
{
    __shared__ float sp[6 * NL];        // [k][stroke], k=0..5 warp rows
    __shared__ float sc[3 * NL];        // [ch][stroke] colors
    __shared__ int   sbo[NL];           // brush base offset (0 or BSZ*BSZ)

    const int t  = threadIdx.x;
    const int b  = blockIdx.x >> 9;     // 512 blocks per batch (32 px/block)
    const int sb = b * NL;

    // ---- fused warp prep: stroke sb+t -> LDS (exact ref rounding) ----
    {
        const float* __restrict__ p = params + (size_t)(sb + t) * 8;
        float x0 = p[0], y0 = p[1], w = p[2], h = p[3], th = p[4];
        float c5 = p[5], c6 = p[6], c7 = p[7];
        float ang = __fmul_rn(3.14159265358979323846f, th);
        double ds, dc;
        sincos((double)ang, &ds, &dc);  // correctly-rounded f32 after cast
        float sin_t = (float)ds;
        float cos_t = (float)dc;
        float a_x = __fsub_rn(1.0f, __fmul_rn(2.0f, x0));
        float a_y = __fsub_rn(1.0f, __fmul_rn(2.0f, y0));
        // H==W==128 -> the H/W aspect factors are exactly 1.0
        sp[0 * NL + t] = __fdiv_rn(cos_t, w);
        sp[1 * NL + t] = __fdiv_rn(sin_t, w);
        sp[2 * NL + t] = __fadd_rn(__fdiv_rn(__fmul_rn(a_x, cos_t), w),
                                   __fdiv_rn(__fmul_rn(a_y, sin_t), w));
        sp[3 * NL + t] = __fdiv_rn(-sin_t, h);
        sp[4 * NL + t] = __fdiv_rn(cos_t, h);
        sp[5 * NL + t] = __fsub_rn(__fdiv_rn(__fmul_rn(a_y, cos_t), h),
                                   __fdiv_rn(__fmul_rn(a_x, sin_t), h));
        sc[0 * NL + t] = c5;
        sc[1 * NL + t] = c6;
        sc[2 * NL + t] = c7;
        sbo[t] = (h > w) ? 0 : BSZ * BSZ;   // idx=where(h>w,0,1)
    }
    __syncthreads();

    const int lane = t & 63;
    const int wid  = t >> 6;
    const int wave = blockIdx.x * 4 + wid;      // 0..8191
    const int g    = lane >> 3;                 // pixel group 0..7
    const int j    = lane & 7;                  // stroke sub-index 0..7
    const int P    = wave * 8 + g;              // global pixel id 0..65535
    const int pix  = P & 16383;
    const int py   = pix >> 7;
    const int px   = pix & 127;

    // per-pixel constants (uniform within each 8-lane group)
    float xs1, ys1, xlo, xhi, ylo, yhi;
    {
        float xs[3], ys[3];
#pragma unroll
        for (int d = 0; d < 3; ++d) {
            int qx = px + d - 1, qy = py + d - 1;
            xs[d] = (2.0f * (float)qx + 1.0f) / 128.0f - 1.0f;   // exact in f32
            ys[d] = (2.0f * (float)qy + 1.0f) / 128.0f - 1.0f;
        }
        xs1 = xs[1]; ys1 = ys[1];
        // inactive erosion taps duplicate the (always-active) center coord;
        // result stays monotone, so only the endpoints matter.
        xlo = (px - 1 >= 0) ? xs[0] : xs1;
        xhi = (px + 1 < IW) ? xs[2] : xs1;
        ylo = (py - 1 >= 0) ? ys[0] : ys1;
        yhi = (py + 1 < IH) ? ys[2] : ys1;
    }

    const size_t pixo = (size_t)py * IW + px;
    const size_t img  = (size_t)b * 3 * IH * IW;
    bool gfound = false;
    bool winner = false;
    int  wls    = 0;

    for (int c = 0; c < 32; ++c) {
        bool cov = false;
        int ls = 0;

        if (!gfound) {
            ls = (NL - 8 - 8 * c) + j;          // local stroke id, chunk from top
            const float w00 = sp[0 * NL + ls];
            const float w01 = sp[1 * NL + ls];
            const float w02 = sp[2 * NL + ls];
            const float w10 = sp[3 * NL + ls];
            const float w11 = sp[4 * NL + ls];
            const float w12 = sp[5 * NL + ls];

            // endpoint selection by coefficient sign (see header proof)
            float xa = (w00 >= 0.0f) ? xlo : xhi;   // minimizes x*w00
            float xb = (w00 >= 0.0f) ? xhi : xlo;   // maximizes x*w00
            float ya = (w01 >= 0.0f) ? ylo : yhi;
            float yb = (w01 >= 0.0f) ? yhi : ylo;
            float xc = (w10 >= 0.0f) ? xlo : xhi;
            float xd = (w10 >= 0.0f) ? xhi : xlo;
            float ye = (w11 >= 0.0f) ? ylo : yhi;
            float yf = (w11 >= 0.0f) ? yhi : ylo;

            float gxmin = __fadd_rn(__fadd_rn(__fmul_rn(xa, w00), __fmul_rn(ya, w01)), w02);
            float gxmax = __fadd_rn(__fadd_rn(__fmul_rn(xb, w00), __fmul_rn(yb, w01)), w02);
            float gymin = __fadd_rn(__fadd_rn(__fmul_rn(xc, w10), __fmul_rn(ye, w11)), w12);
            float gymax = __fadd_rn(__fadd_rn(__fmul_rn(xd, w10), __fmul_rn(yf, w11)), w12);

            cov = (gxmin >= -1.0f) && (gxmax < 1.0f) &&
                  (gymin >= -1.0f) && (gymax < 1.0f);
        }

        const unsigned long long m = __ballot(cov);
        const unsigned mg = (unsigned)(m >> (g * 8)) & 0xFFu;

        if (!gfound && mg != 0u) {
            const int jw = 31 - __clz(mg);      // highest covering stroke in chunk
            if (j == jw) { winner = true; wls = ls; }
            gfound = true;
        }

        if (__ballot(!gfound) == 0ull) break;
    }

    // ---- deferred epilogue: all winner lanes of the wave fetch together ----
    if (winner) {
        const int ls = wls;
        const float w00 = sp[0 * NL + ls];
        const float w01 = sp[1 * NL + ls];
        const float w02 = sp[2 * NL + ls];
        const float w10 = sp[3 * NL + ls];
        const float w11 = sp[4 * NL + ls];
        const float w12 = sp[5 * NL + ls];
        const float* __restrict__ br = brushes + sbo[ls];
        float gx = __fadd_rn(__fadd_rn(__fmul_rn(xs1, w00), __fmul_rn(ys1, w01)), w02);
        float gy = __fadd_rn(__fadd_rn(__fmul_rn(xs1, w10), __fmul_rn(ys1, w11)), w12);
        float xq = __fmul_rn(__fsub_rn(__fmul_rn(__fadd_rn(gx, 1.0f), 512.0f), 1.0f), 0.5f);
        float yq = __fmul_rn(__fsub_rn(__fmul_rn(__fadd_rn(gy, 1.0f), 512.0f), 1.0f), 0.5f);
        float xf = floorf(xq), yf = floorf(yq);
        int   x0i = (int)xf, y0i = (int)yf;
        float wx1 = __fsub_rn(xq, xf), wy1 = __fsub_rn(yq, yf);
        float wx0 = __fsub_rn(1.0f, wx1), wy0 = __fsub_rn(1.0f, wy1);
        float v00 = bil_tap(br, x0i,     y0i);
        float v10 = bil_tap(br, x0i + 1, y0i);
        float v01 = bil_tap(br, x0i,     y0i + 1);
        float v11 = bil_tap(br, x0i + 1, y0i + 1);
        float sv = __fadd_rn(__fadd_rn(__fadd_rn(
                       __fmul_rn(v00, __fmul_rn(wx0, wy0)),
                       __fmul_rn(v10, __fmul_rn(wx1, wy0))),
                       __fmul_rn(v01, __fmul_rn(wx0, wy1))),
                       __fmul_rn(v11, __fmul_rn(wx1, wy1)));
        out[img + 0 * (IH * IW) + pixo] = __fmul_rn(sv, sc[0 * NL + ls]);
        out[img + 1 * (IH * IW) + pixo] = __fmul_rn(sv, sc[1 * NL + ls]);
        out[img + 2 * (IH * IW) + pixo] = __fmul_rn(sv, sc[2 * NL + ls]);
    }

    if (!gfound && j == 0) {
        out[img + 0 * (IH * IW) + pixo] = 0.0f;
        out[img + 1 * (IH * IW) + pixo] = 0.0f;
        out[img + 2 * (IH * IW) + pixo] = 0.0f;
    }
}

extern "C" void kernel_launch(void* const* d_in, const int* in_sizes, int n_in,
                              void* d_out, int out_size, void* d_ws, size_t ws_size,
                              hipStream_t stream) {
    const float* params  = (const float*)d_in[0];   // (4,256,8) f32
    const float* brushes = (const float*)d_in[1];   // (2,1,512,512) f32
    float* out = (float*)d_out;                     // (4,3,128,128) f32
    (void)d_ws; (void)ws_size;                      // workspace not used

    // 65536 pixels / (8 pixels per wave * 4 waves per block) = 2048 blocks
    render_strokes<<<2048, 256, 0, stream>>>(brushes, params, out);
}